// Round 2
// baseline (594.660 us; speedup 1.0000x reference)
//
#include <hip/hip_runtime.h>

#define NN 100000
#define D 64
#define BN_EPS 1e-5f

// ---------------- degree ----------------
__global__ void k_deg_init(float* deg, int n) {
    int i = blockIdx.x * blockDim.x + threadIdx.x;
    if (i < n) deg[i] = 1.0f;  // self-loop weight
}

__global__ void k_deg_edges(const int* __restrict__ src, const int* __restrict__ dst,
                            float* deg, int E) {
    int e = blockIdx.x * blockDim.x + threadIdx.x;
    if (e < E) {
        int s = src[e], d = dst[e];
        if (s != d) atomicAdd(&deg[d], 1.0f);
    }
}

__global__ void k_dinv(float* deg, int n) {
    int i = blockIdx.x * blockDim.x + threadIdx.x;
    if (i < n) deg[i] = rsqrtf(deg[i]);  // deg >= 1 always (self loop)
}

// ---------------- out init: self-loop term (aggregate raw x) ----------------
__global__ void k_agg_init(const float* __restrict__ x, const float* __restrict__ dinv,
                           float* __restrict__ out, int n) {
    int i = blockIdx.x * blockDim.x + threadIdx.x;
    if (i < n * D) {
        int row = i >> 6;
        float di = dinv[row];
        out[i] = x[i] * di * di;
    }
}

// ---------------- edge scatter of raw x: one wave per edge, lane = channel ----------------
__global__ __launch_bounds__(256) void k_scatter(const int* __restrict__ src,
                                                 const int* __restrict__ dst,
                                                 const float* __restrict__ x,
                                                 const float* __restrict__ dinv,
                                                 float* out, int E) {
    int gw = (int)((blockIdx.x * blockDim.x + threadIdx.x) >> 6);
    int lane = threadIdx.x & 63;
    if (gw >= E) return;
    int s = src[gw], d = dst[gw];
    if (s == d) return;  // existing self-loops get zero weight
    float w = dinv[s] * dinv[d];
    float v = x[(size_t)s * D + lane] * w;
    atomicAdd(&out[(size_t)d * D + lane], v);
}

// ---------------- in-place GEMM: row @ W (64x64), one wave per row ----------------
__global__ __launch_bounds__(256) void k_gemm_inplace(float* __restrict__ out,
                                                      const float* __restrict__ W,
                                                      int n) {
    __shared__ float Ws[64 * 64];
    int tid = threadIdx.x;
    for (int i = tid; i < 64 * 64; i += 256) Ws[i] = W[i];
    __syncthreads();
    int wave = tid >> 6, lane = tid & 63;
    int row = blockIdx.x * 4 + wave;
    if (row >= n) return;
    float xv = out[(size_t)row * D + lane];  // row held across the wave's registers
    float acc = 0.0f;
#pragma unroll
    for (int k = 0; k < 64; ++k) {
        acc += __shfl(xv, k) * Ws[k * 64 + lane];
    }
    out[(size_t)row * D + lane] = acc;  // safe: xv already in registers
}

// ---------------- BN stats ----------------
__global__ void k_zero_stats(float* sums) {
    int i = threadIdx.x;
    if (i < 128) sums[i] = 0.0f;
}

__global__ __launch_bounds__(256) void k_bn_stats(const float* __restrict__ out,
                                                  float* sums, int n) {
    int lane = threadIdx.x & 63;
    int wave = threadIdx.x >> 6;
    float s = 0.0f, sq = 0.0f;
    for (int row = blockIdx.x * 4 + wave; row < n; row += gridDim.x * 4) {
        float v = out[(size_t)row * D + lane];
        s += v;
        sq += v * v;
    }
    __shared__ float ls[4][64], lq[4][64];
    ls[wave][lane] = s;
    lq[wave][lane] = sq;
    __syncthreads();
    if (wave == 0) {
        float ts = ls[0][lane] + ls[1][lane] + ls[2][lane] + ls[3][lane];
        float tq = lq[0][lane] + lq[1][lane] + lq[2][lane] + lq[3][lane];
        atomicAdd(&sums[lane], ts);
        atomicAdd(&sums[64 + lane], tq);
    }
}

// ---------------- BN apply + ReLU (in place on d_out) ----------------
// The GCN bias b cancels exactly in BatchNorm (constant per-column shift): omitted.
__global__ void k_bn_apply(float* out, const float* __restrict__ sums,
                           const float* __restrict__ bnw, const float* __restrict__ bnb,
                           int n) {
    int i = blockIdx.x * blockDim.x + threadIdx.x;
    if (i >= n * D) return;
    int c = i & 63;
    const float invn = 1.0f / (float)NN;
    float mean = sums[c] * invn;
    float var = sums[64 + c] * invn - mean * mean;
    if (var < 0.0f) var = 0.0f;
    float scale = bnw[c] * rsqrtf(var + BN_EPS);
    float v = (out[i] - mean) * scale + bnb[c];
    out[i] = v > 0.0f ? v : 0.0f;
}

extern "C" void kernel_launch(void* const* d_in, const int* in_sizes, int n_in,
                              void* d_out, int out_size, void* d_ws, size_t ws_size,
                              hipStream_t stream) {
    const float* x = (const float*)d_in[0];
    const int* ei = (const int*)d_in[1];
    // d_in[2] = num_nodes (device scalar, unused; N from in_sizes)
    const float* W = (const float*)d_in[3];
    // d_in[4] = b, cancels in BN
    const float* bnw = (const float*)d_in[5];
    const float* bnb = (const float*)d_in[6];
    float* out = (float*)d_out;

    const int n = in_sizes[0] / D;       // 100000
    const int E = in_sizes[1] / 2;       // 1600000
    const int* src = ei;
    const int* dst = ei + E;

    // minimal workspace: dinv (n floats) + sums (128 floats)  ~400 KB
    float* dinv = (float*)d_ws;
    float* sums = dinv + n;

    k_deg_init<<<(n + 255) / 256, 256, 0, stream>>>(dinv, n);
    k_deg_edges<<<(E + 255) / 256, 256, 0, stream>>>(src, dst, dinv, E);
    k_dinv<<<(n + 255) / 256, 256, 0, stream>>>(dinv, n);

    k_agg_init<<<(n * D + 255) / 256, 256, 0, stream>>>(x, dinv, out, n);
    k_scatter<<<(E + 3) / 4, 256, 0, stream>>>(src, dst, x, dinv, out, E);

    k_gemm_inplace<<<(n + 3) / 4, 256, 0, stream>>>(out, W, n);

    k_zero_stats<<<1, 128, 0, stream>>>(sums);
    k_bn_stats<<<1024, 256, 0, stream>>>(out, sums, n);
    k_bn_apply<<<(n * D + 255) / 256, 256, 0, stream>>>(out, sums, bnw, bnb, n);
}